// Round 1
// baseline (8698.813 us; speedup 1.0000x reference)
//
#include <hip/hip_runtime.h>
#include <hip/hip_bf16.h>

// Dims
#define E_ 256
#define H_ 256
#define B_ 64
#define S_ 512
#define T_ 12
#define START_ 10
#define STOP_ 11
#define NEG_ -10000.0f

typedef __attribute__((ext_vector_type(8))) short bf16x8;
typedef __attribute__((ext_vector_type(4))) float f32x4;

__device__ inline __hip_bfloat16 f2bf(float x) { return __float2bfloat16(x); }
__device__ inline float bf2f(__hip_bfloat16 x) { return __bfloat162float(x); }
__device__ inline unsigned short f2us(float f) {
    __hip_bfloat16 h = __float2bfloat16(f);
    unsigned short u; __builtin_memcpy(&u, &h, 2); return u;
}
__device__ inline float us2f(unsigned short u) {
    unsigned int x = ((unsigned int)u) << 16;
    float f; __builtin_memcpy(&f, &x, 4); return f;
}
__device__ inline float sigm_(float x) {
    return __builtin_amdgcn_rcpf(1.f + __builtin_amdgcn_exp2f(-1.44269504f * x));
}
__device__ inline float tanh_(float x) {
    return 2.f * __builtin_amdgcn_rcpf(1.f + __builtin_amdgcn_exp2f(-2.88539008f * x)) - 1.f;
}

// ---------------- prep: cast weights to bf16, fold biases ----------------
// wb[2048][256]  = [wih_f ; wih_b], whhb[2048][256] = [whh_f ; whh_b]
// bias[2048] = [bih_f+bhh_f ; bih_b+bhh_b]
__global__ void k_prep(const float* wih_f, const float* whh_f,
                       const float* bih_f, const float* bhh_f,
                       const float* wih_b, const float* whh_b,
                       const float* bih_b, const float* bhh_b,
                       __hip_bfloat16* wb, __hip_bfloat16* whhb, float* bias)
{
    int i = blockIdx.x * 256 + threadIdx.x;   // 0 .. 524287
    int n = i >> 8, k = i & 255;
    float wi = (n < 1024) ? wih_f[n * 256 + k] : wih_b[(n - 1024) * 256 + k];
    float wh = (n < 1024) ? whh_f[n * 256 + k] : whh_b[(n - 1024) * 256 + k];
    wb[i] = f2bf(wi);
    whhb[i] = f2bf(wh);
    if (i < 2048)
        bias[i] = (i < 1024) ? (bih_f[i] + bhh_f[i]) : (bih_b[i - 1024] + bhh_b[i - 1024]);
}

// ---------------- gather: xb[s*64+b][e] = bf16(emb[sent[b][s]][e]) ----------------
__global__ void k_gather(const int* sent, const float* emb, __hip_bfloat16* xb)
{
    int gid = blockIdx.x * 256 + threadIdx.x;   // 32768 rows * 64 lanes
    int row = gid >> 6;                          // s*64 + b
    int l = gid & 63;
    int s = row >> 6, b = row & 63;
    int tok = sent[b * S_ + s];
    const float4 v = *reinterpret_cast<const float4*>(emb + (size_t)tok * E_ + l * 4);
    ushort4 pk;
    pk.x = f2us(v.x); pk.y = f2us(v.y); pk.z = f2us(v.z); pk.w = f2us(v.w);
    *reinterpret_cast<ushort4*>(xb + (size_t)row * E_ + l * 4) = pk;
}

// ---------------- pre-GEMM: pre[dir][s][b][j] = xb @ wb^T + bias ----------------
// M=32768 (s*64+b), N=2048 (dir*1024+j), K=256. Tile 64x64, 4 waves, direct-from-L2 frags.
__global__ void k_pregemm(const __hip_bfloat16* xb, const __hip_bfloat16* wb,
                          const float* bias, __hip_bfloat16* pre)
{
    int m0 = blockIdx.x * 64;
    int n0 = blockIdx.y * 64;
    int w = threadIdx.x >> 6, l = threadIdx.x & 63;
    int lr = l & 15, lk = (l >> 4) * 8;
    const __hip_bfloat16* ap = xb + (size_t)(m0 + w * 16 + lr) * 256 + lk;
    const __hip_bfloat16* bpp = wb + (size_t)(n0 + lr) * 256 + lk;
    f32x4 acc[4] = {};
#pragma unroll
    for (int kc = 0; kc < 8; ++kc) {
        bf16x8 a = *reinterpret_cast<const bf16x8*>(ap + kc * 32);
#pragma unroll
        for (int f = 0; f < 4; ++f) {
            bf16x8 bb = *reinterpret_cast<const bf16x8*>(bpp + f * 16 * 256 + kc * 32);
            acc[f] = __builtin_amdgcn_mfma_f32_16x16x32_bf16(a, bb, acc[f], 0, 0, 0);
        }
    }
#pragma unroll
    for (int f = 0; f < 4; ++f) {
        int n = n0 + f * 16 + lr;
        float bs = bias[n];
        int dir = n >> 10, j = n & 1023;
#pragma unroll
        for (int q = 0; q < 4; ++q) {
            int m = m0 + w * 16 + (l >> 4) * 4 + q;
            pre[(size_t)dir * 33554432 + (size_t)m * 1024 + j] = f2bf(acc[f][q] + bs);
        }
    }
}

// ---------------- recurrent LSTM: 8 persistent WGs (2 dir x 4 batch-slices) ----------------
// Each WG: 16 batches, h in LDS (double-buffered bf16), c in regs, Whh streamed from L2.
__launch_bounds__(512)
__global__ void k_lstm(const __hip_bfloat16* whhb, const __hip_bfloat16* pre,
                       const float* h0, const float* c0, __hip_bfloat16* hout)
{
    __shared__ __hip_bfloat16 hbuf[2][16][264];   // +8 pad -> conflict-free-ish b128 reads
    int dir = blockIdx.x >> 2;
    int b0 = (blockIdx.x & 3) * 16;
    int tid = threadIdx.x;
    int w = tid >> 6, l = tid & 63;
    int lr = l & 15, lh = l >> 4;   // lh in 0..3
    int lk = lh * 8;

    // init h -> hbuf[0]
    {
        int r = tid >> 5, k = (tid & 31) * 8;
        const float* src = h0 + (size_t)(dir * 64 + b0 + r) * 256 + k;
#pragma unroll
        for (int i = 0; i < 8; ++i) hbuf[0][r][k + i] = f2bf(src[i]);
    }
    // init c in regs; layout matches MFMA D frag: row b = b0+lh*4+q, col k = w*32+hh*16+lr
    float c[2][4];
#pragma unroll
    for (int hh = 0; hh < 2; ++hh)
#pragma unroll
        for (int q = 0; q < 4; ++q)
            c[hh][q] = c0[(size_t)(dir * 64 + b0 + lh * 4 + q) * 256 + w * 32 + hh * 16 + lr];
    __syncthreads();

    const __hip_bfloat16* wp = whhb + (size_t)dir * 1024 * 256;
    const __hip_bfloat16* prebase = pre + (size_t)dir * 33554432;
    __hip_bfloat16* hop = hout + (size_t)dir * 8388608;

    for (int t = 0; t < 512; ++t) {
        int s = dir ? (511 - t) : t;
        int cur = t & 1, nxt = cur ^ 1;

        // prefetch pre[t] for this step (consumed after MFMA -> latency hidden)
        __hip_bfloat16 preg[8][4];
        const __hip_bfloat16* pb = prebase + (size_t)(s * 64 + b0) * 1024;
#pragma unroll
        for (int f = 0; f < 8; ++f) {
            int n = (f >> 1) * 256 + w * 32 + (f & 1) * 16 + lr;
#pragma unroll
            for (int q = 0; q < 4; ++q)
                preg[f][q] = pb[(size_t)(lh * 4 + q) * 1024 + n];
        }

        f32x4 acc[8] = {};
#pragma unroll
        for (int kc = 0; kc < 8; ++kc) {
            bf16x8 a = *reinterpret_cast<const bf16x8*>(&hbuf[cur][lr][kc * 32 + lk]);
#pragma unroll
            for (int f = 0; f < 8; ++f) {
                int n = (f >> 1) * 256 + w * 32 + (f & 1) * 16 + lr;
                bf16x8 bb = *reinterpret_cast<const bf16x8*>(wp + (size_t)n * 256 + kc * 32 + lk);
                acc[f] = __builtin_amdgcn_mfma_f32_16x16x32_bf16(a, bb, acc[f], 0, 0, 0);
            }
        }

        // gates: f index = gate*2 + half; gates order i,f,g,o
#pragma unroll
        for (int hh = 0; hh < 2; ++hh) {
#pragma unroll
            for (int q = 0; q < 4; ++q) {
                float iv = acc[0 + hh][q] + bf2f(preg[0 + hh][q]);
                float fv = acc[2 + hh][q] + bf2f(preg[2 + hh][q]);
                float gv = acc[4 + hh][q] + bf2f(preg[4 + hh][q]);
                float ov = acc[6 + hh][q] + bf2f(preg[6 + hh][q]);
                float cn = sigm_(fv) * c[hh][q] + sigm_(iv) * tanh_(gv);
                c[hh][q] = cn;
                float hv = sigm_(ov) * tanh_(cn);
                __hip_bfloat16 hb = f2bf(hv);
                int r = lh * 4 + q, k = w * 32 + hh * 16 + lr;
                hbuf[nxt][r][k] = hb;
                hop[(size_t)(s * 64 + b0 + r) * 256 + k] = hb;
            }
        }
        __syncthreads();
    }
}

// ---------------- feats: [s*64+b][tag] = [hf|hb] . w_out[tag] + b_out ----------------
__global__ void k_feats(const __hip_bfloat16* hout, const float* w_out, const float* b_out,
                        float* feats)
{
    __shared__ float wsm[12 * 512];
    __shared__ float bsm[12];
    int tid = threadIdx.x;
    for (int i = tid; i < 12 * 512; i += 256) wsm[i] = w_out[i];
    if (tid < 12) bsm[tid] = b_out[tid];
    __syncthreads();
    int w = tid >> 6, l = tid & 63;
    int row = blockIdx.x * 4 + w;
    const ushort4 uf = *reinterpret_cast<const ushort4*>(hout + (size_t)row * 256 + l * 4);
    const ushort4 ub = *reinterpret_cast<const ushort4*>(hout + 8388608 + (size_t)row * 256 + l * 4);
    float hf[4] = { us2f(uf.x), us2f(uf.y), us2f(uf.z), us2f(uf.w) };
    float hb[4] = { us2f(ub.x), us2f(ub.y), us2f(ub.z), us2f(ub.w) };
    float outv[12];
#pragma unroll
    for (int tg = 0; tg < 12; ++tg) {
        const float* wr = &wsm[tg * 512];
        float v = 0.f;
#pragma unroll
        for (int i = 0; i < 4; ++i)
            v += wr[l * 4 + i] * hf[i] + wr[256 + l * 4 + i] * hb[i];
#pragma unroll
        for (int off = 32; off >= 1; off >>= 1) v += __shfl_xor(v, off, 64);
        outv[tg] = v;
    }
    if (l == 0) {
#pragma unroll
        for (int tg = 0; tg < 12; ++tg)
            feats[(size_t)row * 12 + tg] = outv[tg] + bsm[tg];
    }
}

// ---------------- Viterbi DP + backtrace: one wave per sequence ----------------
__global__ void k_viterbi(const float* feats, const float* trans, float* out)
{
    __shared__ unsigned char bp[512][12];
    __shared__ float red[12];
    int b = blockIdx.x, l = threadIdx.x;
    bool act = l < 12;
    float trow[12];
#pragma unroll
    for (int p = 0; p < 12; ++p) trow[p] = act ? trans[l * 12 + p] : 0.f;
    float fv = (l == START_) ? 0.f : NEG_;
    for (int t = 0; t < 512; ++t) {
        float best = -3.0e38f; int bi = 0;
#pragma unroll
        for (int p = 0; p < 12; ++p) {
            float fp = __shfl(fv, p, 64) + trow[p];
            if (fp > best) { best = fp; bi = p; }   // strict > keeps FIRST max (np semantics)
        }
        float ft = act ? feats[(size_t)(t * 64 + b) * 12 + l] : 0.f;
        fv = best + ft;
        if (act) bp[t][l] = (unsigned char)bi;
    }
    float term = fv + (act ? trans[STOP_ * 12 + l] : 0.f);
    if (act) red[l] = term;
    __syncthreads();
    if (l == 0) {
        float bv = red[0]; int bestj = 0;
#pragma unroll
        for (int j = 1; j < 12; ++j)
            if (red[j] > bv) { bv = red[j]; bestj = j; }
        out[b] = bv;
        int curtag = bestj;
        for (int t = 511; t >= 0; --t) {
            out[64 + (size_t)b * 512 + t] = (float)curtag;
            curtag = bp[t][curtag];
        }
    }
}

extern "C" void kernel_launch(void* const* d_in, const int* in_sizes, int n_in,
                              void* d_out, int out_size, void* d_ws, size_t ws_size,
                              hipStream_t stream)
{
    const int*   sent  = (const int*)  d_in[0];
    const float* emb   = (const float*)d_in[1];
    const float* wih_f = (const float*)d_in[2];
    const float* whh_f = (const float*)d_in[3];
    const float* bih_f = (const float*)d_in[4];
    const float* bhh_f = (const float*)d_in[5];
    const float* wih_b = (const float*)d_in[6];
    const float* whh_b = (const float*)d_in[7];
    const float* bih_b = (const float*)d_in[8];
    const float* bhh_b = (const float*)d_in[9];
    const float* w_out = (const float*)d_in[10];
    const float* b_out = (const float*)d_in[11];
    const float* trans = (const float*)d_in[12];
    const float* h0    = (const float*)d_in[13];
    const float* c0    = (const float*)d_in[14];
    float* out = (float*)d_out;

    char* ws = (char*)d_ws;
    __hip_bfloat16* xb    = (__hip_bfloat16*)(ws);               // 16,777,216 B
    __hip_bfloat16* wb    = (__hip_bfloat16*)(ws + 16777216);    //  1,048,576 B
    __hip_bfloat16* whhb  = (__hip_bfloat16*)(ws + 17825792);    //  1,048,576 B
    float*          bias  = (float*)         (ws + 18874368);    //      8,192 B
    __hip_bfloat16* pre   = (__hip_bfloat16*)(ws + 18882560);    // 134,217,728 B
    __hip_bfloat16* hout  = (__hip_bfloat16*)(ws + 153100288);   // 33,554,432 B
    float*          feats = (float*)         (ws + 186654720);   //  1,572,864 B
    // total 188,227,584 B

    hipLaunchKernelGGL(k_prep, dim3(2048), dim3(256), 0, stream,
                       wih_f, whh_f, bih_f, bhh_f, wih_b, whh_b, bih_b, bhh_b,
                       wb, whhb, bias);
    hipLaunchKernelGGL(k_gather, dim3(8192), dim3(256), 0, stream, sent, emb, xb);
    hipLaunchKernelGGL(k_pregemm, dim3(512, 32), dim3(256), 0, stream, xb, wb, bias, pre);
    hipLaunchKernelGGL(k_lstm, dim3(8), dim3(512), 0, stream, whhb, pre, h0, c0, hout);
    hipLaunchKernelGGL(k_feats, dim3(8192), dim3(256), 0, stream, hout, w_out, b_out, feats);
    hipLaunchKernelGGL(k_viterbi, dim3(64), dim3(64), 0, stream, feats, trans, out);
}

// Round 3
// 2626.008 us; speedup vs baseline: 3.3126x; 3.3126x over previous
//
#include <hip/hip_runtime.h>
#include <hip/hip_bf16.h>

// Dims
#define E_ 256
#define H_ 256
#define B_ 64
#define S_ 512
#define T_ 12
#define START_ 10
#define STOP_ 11
#define NEG_ -10000.0f

typedef __attribute__((ext_vector_type(8))) short bf16x8;
typedef __attribute__((ext_vector_type(4))) float f32x4;

__device__ inline __hip_bfloat16 f2bf(float x) { return __float2bfloat16(x); }
__device__ inline float bf2f(__hip_bfloat16 x) { return __bfloat162float(x); }
__device__ inline unsigned short f2us(float f) {
    __hip_bfloat16 h = __float2bfloat16(f);
    unsigned short u; __builtin_memcpy(&u, &h, 2); return u;
}
__device__ inline float us2f(unsigned short u) {
    unsigned int x = ((unsigned int)u) << 16;
    float f; __builtin_memcpy(&f, &x, 4); return f;
}
__device__ inline float sigm_(float x) {
    return __builtin_amdgcn_rcpf(1.f + __builtin_amdgcn_exp2f(-1.44269504f * x));
}
__device__ inline float tanh_(float x) {
    return 2.f * __builtin_amdgcn_rcpf(1.f + __builtin_amdgcn_exp2f(-2.88539008f * x)) - 1.f;
}

// ---------------- prep: cast weights to bf16, fold biases ----------------
__global__ void k_prep(const float* wih_f, const float* whh_f,
                       const float* bih_f, const float* bhh_f,
                       const float* wih_b, const float* whh_b,
                       const float* bih_b, const float* bhh_b,
                       __hip_bfloat16* wb, __hip_bfloat16* whhb, float* bias)
{
    int i = blockIdx.x * 256 + threadIdx.x;   // 0 .. 524287
    int n = i >> 8, k = i & 255;
    float wi = (n < 1024) ? wih_f[n * 256 + k] : wih_b[(n - 1024) * 256 + k];
    float wh = (n < 1024) ? whh_f[n * 256 + k] : whh_b[(n - 1024) * 256 + k];
    wb[i] = f2bf(wi);
    whhb[i] = f2bf(wh);
    if (i < 2048)
        bias[i] = (i < 1024) ? (bih_f[i] + bhh_f[i]) : (bih_b[i - 1024] + bhh_b[i - 1024]);
}

// ---------------- zero the step flags ----------------
__global__ void k_zeroflags(int* flags)
{
    flags[blockIdx.x * 256 + threadIdx.x] = 0;
}

// ---------------- gather: xb[s*64+b][e] = bf16(emb[sent[b][s]][e]) ----------------
__global__ void k_gather(const int* sent, const float* emb, __hip_bfloat16* xb)
{
    int gid = blockIdx.x * 256 + threadIdx.x;   // 32768 rows * 64 lanes
    int row = gid >> 6;                          // s*64 + b
    int l = gid & 63;
    int s = row >> 6, b = row & 63;
    int tok = sent[b * S_ + s];
    const float4 v = *reinterpret_cast<const float4*>(emb + (size_t)tok * E_ + l * 4);
    ushort4 pk;
    pk.x = f2us(v.x); pk.y = f2us(v.y); pk.z = f2us(v.z); pk.w = f2us(v.w);
    *reinterpret_cast<ushort4*>(xb + (size_t)row * E_ + l * 4) = pk;
}

// ---------------- pre-GEMM: pre[dir][s][b][j] = xb @ wb^T + bias ----------------
__global__ void k_pregemm(const __hip_bfloat16* xb, const __hip_bfloat16* wb,
                          const float* bias, __hip_bfloat16* pre)
{
    int m0 = blockIdx.x * 64;
    int n0 = blockIdx.y * 64;
    int w = threadIdx.x >> 6, l = threadIdx.x & 63;
    int lr = l & 15, lk = (l >> 4) * 8;
    const __hip_bfloat16* ap = xb + (size_t)(m0 + w * 16 + lr) * 256 + lk;
    const __hip_bfloat16* bpp = wb + (size_t)(n0 + lr) * 256 + lk;
    f32x4 acc[4] = {};
#pragma unroll
    for (int kc = 0; kc < 8; ++kc) {
        bf16x8 a = *reinterpret_cast<const bf16x8*>(ap + kc * 32);
#pragma unroll
        for (int f = 0; f < 4; ++f) {
            bf16x8 bb = *reinterpret_cast<const bf16x8*>(bpp + f * 16 * 256 + kc * 32);
            acc[f] = __builtin_amdgcn_mfma_f32_16x16x32_bf16(a, bb, acc[f], 0, 0, 0);
        }
    }
#pragma unroll
    for (int f = 0; f < 4; ++f) {
        int n = n0 + f * 16 + lr;
        float bs = bias[n];
        int dir = n >> 10, j = n & 1023;
#pragma unroll
        for (int q = 0; q < 4; ++q) {
            int m = m0 + w * 16 + (l >> 4) * 4 + q;
            pre[(size_t)dir * 33554432 + (size_t)m * 1024 + j] = f2bf(acc[f][q] + bs);
        }
    }
}

// ---------------- recurrent LSTM: 32 WGs, register-resident Whh ----------------
// WG = (dir, batch-slice of 16, j-slice of 64 h-cols). 4 waves of 64.
// Each wave: 16 j-cols x 4 gates (n = g*256 + jsub+lr), M=16 batches, K=256.
// Whh fragment (128 KB/WG -> 128 VGPR/lane) loaded ONCE before the time loop.
// Per step: peers' h_{t-1} read from hout via agent-scope atomics; 4-WG flag barrier.
__launch_bounds__(256)
__global__ void k_lstm_sync(const __hip_bfloat16* whhb, const __hip_bfloat16* pre,
                            const float* h0, const float* c0, __hip_bfloat16* hout,
                            int* flags)
{
    int bid = blockIdx.x;
    int dir = bid >> 4;          // 0..1
    int bs  = (bid >> 2) & 3;    // batch slice
    int jw  = bid & 3;           // j slice
    int b0 = bs * 16;
    int tid = threadIdx.x;
    int w = tid >> 6, l = tid & 63;
    int lr = l & 15, lh = l >> 4, lk = lh * 8;
    int jsub = jw * 64 + w * 16;         // this wave's 16 h-cols

    const __hip_bfloat16* wp = whhb + (size_t)dir * 262144;
    const __hip_bfloat16* prebase = pre + (size_t)dir * 33554432;
    __hip_bfloat16* hop = hout + (size_t)dir * 8388608;
    int* flg = flags + (dir * 4 + bs) * 512;

    // ---- preload Whh fragments: wreg[gate][kc], col = gate*256 + jsub + lr ----
    bf16x8 wreg[4][8];
#pragma unroll
    for (int f = 0; f < 4; ++f) {
        const __hip_bfloat16* base = wp + (size_t)(f * 256 + jsub + lr) * 256 + lk;
#pragma unroll
        for (int kc = 0; kc < 8; ++kc)
            wreg[f][kc] = *reinterpret_cast<const bf16x8*>(base + kc * 32);
    }

    // ---- c state: lane holds rows lh*4+q, col jsub+lr ----
    float c[4];
#pragma unroll
    for (int q = 0; q < 4; ++q)
        c[q] = c0[(size_t)(dir * 64 + b0 + lh * 4 + q) * 256 + jsub + lr];

    for (int t = 0; t < 512; ++t) {
        int s = dir ? (511 - t) : t;

        // issue pre[t] loads early (HBM latency overlaps the flag spin)
        unsigned short pr[4][4];
#pragma unroll
        for (int f = 0; f < 4; ++f)
#pragma unroll
            for (int q = 0; q < 4; ++q)
                pr[f][q] = *reinterpret_cast<const unsigned short*>(
                    prebase + (size_t)(s * 64 + b0 + lh * 4 + q) * 1024 + f * 256 + jsub + lr);

        // ---- A fragments: h_{t-1}, row lr, k = kc*32 + lk ----
        bf16x8 areg[8];
        if (t == 0) {
            const float* hrow = h0 + (size_t)(dir * 64 + b0 + lr) * 256;
#pragma unroll
            for (int kc = 0; kc < 8; ++kc) {
                bf16x8 a;
#pragma unroll
                for (int i = 0; i < 8; ++i)
                    a[i] = (short)f2us(hrow[kc * 32 + lk + i]);
                areg[kc] = a;
            }
        } else {
            if (tid == 0) {
                while (__hip_atomic_load(&flg[t - 1], __ATOMIC_ACQUIRE,
                                         __HIP_MEMORY_SCOPE_AGENT) < 4)
                    __builtin_amdgcn_s_sleep(1);
            }
            __syncthreads();
            int sprev = dir ? (s + 1) : (s - 1);
            const unsigned long long* hr = reinterpret_cast<const unsigned long long*>(
                hop + (size_t)(sprev * 64 + b0 + lr) * 256 + lk);
#pragma unroll
            for (int kc = 0; kc < 8; ++kc) {
                union { unsigned long long u[2]; bf16x8 v; } cv;
                cv.u[0] = __hip_atomic_load(hr + kc * 8, __ATOMIC_RELAXED,
                                            __HIP_MEMORY_SCOPE_AGENT);
                cv.u[1] = __hip_atomic_load(hr + kc * 8 + 1, __ATOMIC_RELAXED,
                                            __HIP_MEMORY_SCOPE_AGENT);
                areg[kc] = cv.v;
            }
        }

        // ---- MFMA: all operands in registers ----
        f32x4 acc[4] = {};
#pragma unroll
        for (int kc = 0; kc < 8; ++kc) {
#pragma unroll
            for (int f = 0; f < 4; ++f)
                acc[f] = __builtin_amdgcn_mfma_f32_16x16x32_bf16(areg[kc], wreg[f][kc],
                                                                 acc[f], 0, 0, 0);
        }

        // ---- gates (i,f,g,o), c update, h write ----
#pragma unroll
        for (int q = 0; q < 4; ++q) {
            float iv = acc[0][q] + us2f(pr[0][q]);
            float fv = acc[1][q] + us2f(pr[1][q]);
            float gv = acc[2][q] + us2f(pr[2][q]);
            float ov = acc[3][q] + us2f(pr[3][q]);
            float cn = sigm_(fv) * c[q] + sigm_(iv) * tanh_(gv);
            c[q] = cn;
            float hv = sigm_(ov) * tanh_(cn);
            unsigned short hb = f2us(hv);
            __hip_atomic_store(
                (unsigned short*)(hop + (size_t)(s * 64 + b0 + lh * 4 + q) * 256 + jsub + lr),
                hb, __ATOMIC_RELAXED, __HIP_MEMORY_SCOPE_AGENT);
        }
        __syncthreads();   // all waves' h stores issued & drained (vmcnt0 at barrier)
        if (tid == 0)
            __hip_atomic_fetch_add(&flg[t], 1, __ATOMIC_RELEASE, __HIP_MEMORY_SCOPE_AGENT);
    }
}

// ---------------- feats ----------------
__global__ void k_feats(const __hip_bfloat16* hout, const float* w_out, const float* b_out,
                        float* feats)
{
    __shared__ float wsm[12 * 512];
    __shared__ float bsm[12];
    int tid = threadIdx.x;
    for (int i = tid; i < 12 * 512; i += 256) wsm[i] = w_out[i];
    if (tid < 12) bsm[tid] = b_out[tid];
    __syncthreads();
    int w = tid >> 6, l = tid & 63;
    int row = blockIdx.x * 4 + w;
    const ushort4 uf = *reinterpret_cast<const ushort4*>(hout + (size_t)row * 256 + l * 4);
    const ushort4 ub = *reinterpret_cast<const ushort4*>(hout + 8388608 + (size_t)row * 256 + l * 4);
    float hf[4] = { us2f(uf.x), us2f(uf.y), us2f(uf.z), us2f(uf.w) };
    float hb[4] = { us2f(ub.x), us2f(ub.y), us2f(ub.z), us2f(ub.w) };
    float outv[12];
#pragma unroll
    for (int tg = 0; tg < 12; ++tg) {
        const float* wr = &wsm[tg * 512];
        float v = 0.f;
#pragma unroll
        for (int i = 0; i < 4; ++i)
            v += wr[l * 4 + i] * hf[i] + wr[256 + l * 4 + i] * hb[i];
#pragma unroll
        for (int off = 32; off >= 1; off >>= 1) v += __shfl_xor(v, off, 64);
        outv[tg] = v;
    }
    if (l == 0) {
#pragma unroll
        for (int tg = 0; tg < 12; ++tg)
            feats[(size_t)row * 12 + tg] = outv[tg] + bsm[tg];
    }
}

// ---------------- Viterbi DP + backtrace ----------------
__global__ void k_viterbi(const float* feats, const float* trans, float* out)
{
    __shared__ unsigned char bp[512][12];
    __shared__ float red[12];
    int b = blockIdx.x, l = threadIdx.x;
    bool act = l < 12;
    float trow[12];
#pragma unroll
    for (int p = 0; p < 12; ++p) trow[p] = act ? trans[l * 12 + p] : 0.f;
    float fv = (l == START_) ? 0.f : NEG_;
    for (int t = 0; t < 512; ++t) {
        float best = -3.0e38f; int bi = 0;
#pragma unroll
        for (int p = 0; p < 12; ++p) {
            float fp = __shfl(fv, p, 64) + trow[p];
            if (fp > best) { best = fp; bi = p; }   // strict > keeps FIRST max (np semantics)
        }
        float ft = act ? feats[(size_t)(t * 64 + b) * 12 + l] : 0.f;
        fv = best + ft;
        if (act) bp[t][l] = (unsigned char)bi;
    }
    float term = fv + (act ? trans[STOP_ * 12 + l] : 0.f);
    if (act) red[l] = term;
    __syncthreads();
    if (l == 0) {
        float bv = red[0]; int bestj = 0;
#pragma unroll
        for (int j = 1; j < 12; ++j)
            if (red[j] > bv) { bv = red[j]; bestj = j; }
        out[b] = bv;
        int curtag = bestj;
        for (int t = 511; t >= 0; --t) {
            out[64 + (size_t)b * 512 + t] = (float)curtag;
            curtag = bp[t][curtag];
        }
    }
}

extern "C" void kernel_launch(void* const* d_in, const int* in_sizes, int n_in,
                              void* d_out, int out_size, void* d_ws, size_t ws_size,
                              hipStream_t stream)
{
    const int*   sent  = (const int*)  d_in[0];
    const float* emb   = (const float*)d_in[1];
    const float* wih_f = (const float*)d_in[2];
    const float* whh_f = (const float*)d_in[3];
    const float* bih_f = (const float*)d_in[4];
    const float* bhh_f = (const float*)d_in[5];
    const float* wih_b = (const float*)d_in[6];
    const float* whh_b = (const float*)d_in[7];
    const float* bih_b = (const float*)d_in[8];
    const float* bhh_b = (const float*)d_in[9];
    const float* w_out = (const float*)d_in[10];
    const float* b_out = (const float*)d_in[11];
    const float* trans = (const float*)d_in[12];
    const float* h0    = (const float*)d_in[13];
    const float* c0    = (const float*)d_in[14];
    float* out = (float*)d_out;

    char* ws = (char*)d_ws;
    __hip_bfloat16* xb    = (__hip_bfloat16*)(ws);               // 16,777,216 B
    __hip_bfloat16* wb    = (__hip_bfloat16*)(ws + 16777216);    //  1,048,576 B
    __hip_bfloat16* whhb  = (__hip_bfloat16*)(ws + 17825792);    //  1,048,576 B
    float*          bias  = (float*)         (ws + 18874368);    //      8,192 B
    __hip_bfloat16* pre   = (__hip_bfloat16*)(ws + 18882560);    // 134,217,728 B
    __hip_bfloat16* hout  = (__hip_bfloat16*)(ws + 153100288);   // 33,554,432 B
    float*          feats = (float*)         (ws + 186654720);   //  1,572,864 B
    int*            flags = (int*)           (ws + 188227584);   //     16,384 B
    // total 188,243,968 B

    hipLaunchKernelGGL(k_prep, dim3(2048), dim3(256), 0, stream,
                       wih_f, whh_f, bih_f, bhh_f, wih_b, whh_b, bih_b, bhh_b,
                       wb, whhb, bias);
    hipLaunchKernelGGL(k_zeroflags, dim3(16), dim3(256), 0, stream, flags);
    hipLaunchKernelGGL(k_gather, dim3(8192), dim3(256), 0, stream, sent, emb, xb);
    hipLaunchKernelGGL(k_pregemm, dim3(512, 32), dim3(256), 0, stream, xb, wb, bias, pre);
    hipLaunchKernelGGL(k_lstm_sync, dim3(32), dim3(256), 0, stream,
                       whhb, pre, h0, c0, hout, flags);
    hipLaunchKernelGGL(k_feats, dim3(8192), dim3(256), 0, stream, hout, w_out, b_out, feats);
    hipLaunchKernelGGL(k_viterbi, dim3(64), dim3(64), 0, stream, feats, trans, out);
}